// Round 11
// baseline (327.908 us; speedup 1.0000x reference)
//
#include <hip/hip_runtime.h>
#include <math.h>

using u16 = unsigned short;
typedef __bf16 bf16x8 __attribute__((ext_vector_type(8)));
typedef float f32x4 __attribute__((ext_vector_type(4)));

#define BB 4
#define NN 4096
#define DD 256
#define DD2 512
#define CC2 1024
static constexpr int ROWS = BB * NN;  // 16384
static constexpr size_t MB = 1024 * 1024;

__device__ __forceinline__ u16 f2bf(float f) {
  union { float f; unsigned u; } v; v.f = f;
  unsigned r = v.u + 0x7fffu + ((v.u >> 16) & 1u);
  return (u16)(r >> 16);
}
__device__ __forceinline__ float bf2f(u16 u) {
  union { unsigned u; float f; } v; v.u = ((unsigned)u) << 16;
  return v.f;
}
__device__ __forceinline__ float u2f(unsigned x) {
  union { unsigned u; float f; } v; v.u = x; return v.f;
}
__device__ __forceinline__ void gload16(const void* g, void* l) {
  __builtin_amdgcn_global_load_lds(
      (const __attribute__((address_space(1))) void*)g,
      (__attribute__((address_space(3))) void*)l, 16, 0, 0);
}

// ---------------- one-shot weight prep ----------------
// segments: w_x1t | w_rept | w_fc1t | w_fc2t | w_cat_b(cast) | w_expt | w_dwt | b_comb
__global__ __launch_bounds__(256) void wprep_all(
    const float* __restrict__ w_x1, const float* __restrict__ w_rep,
    const float* __restrict__ w_fc1, const float* __restrict__ w_fc2,
    const float* __restrict__ w_cat, const float* __restrict__ w_exp,
    const float* __restrict__ w_dw, const float* __restrict__ b_cat,
    u16* __restrict__ w_x1t, u16* __restrict__ w_rept,
    u16* __restrict__ w_fc1t, u16* __restrict__ w_fc2t,
    u16* __restrict__ w_cat_b, u16* __restrict__ w_expt,
    float* __restrict__ w_dwt, float* __restrict__ b_comb) {
  int i = blockIdx.x * 256 + threadIdx.x;
  if (i < 65536) { int n = i >> 8, k = i & 255; w_x1t[i] = f2bf(w_x1[k * 256 + n]); return; }
  i -= 65536;
  if (i < 131072) { int n = i >> 8, k = i & 255; w_rept[i] = f2bf(w_rep[k * 512 + n]); return; }
  i -= 131072;
  if (i < 524288) { int n = i >> 9, k = i & 511; w_fc1t[i] = f2bf(w_fc1[k * 1024 + n]); return; }
  i -= 524288;
  if (i < 524288) { int n = i >> 10, k = i & 1023; w_fc2t[i] = f2bf(w_fc2[k * 512 + n]); return; }
  i -= 524288;
  if (i < 131072) { w_cat_b[i] = f2bf(w_cat[i]); return; }  // [512][256] plain cast
  i -= 131072;
  if (i < 262144) { int n = i >> 8, k = i & 255; w_expt[i] = f2bf(w_exp[k * 1024 + n]); return; }
  i -= 262144;
  if (i < 27648) { int widx = i >> 10, c = i & 1023; w_dwt[i] = w_dw[c * 27 + widx]; return; }
  i -= 27648;
  if (i < 1024) {
    float acc = 0.f;
    for (int o = 0; o < 256; ++o) acc += b_cat[o] * w_exp[o * 1024 + i];
    b_comb[i] = acc;
  }
}

// ---------------- generic 128x128-tile MFMA GEMM ----------------
// A [M][K] bf16 (fp32 when AF32), Bt [N][K] bf16, C row-major [M][Ncols]
// XCD-chunked grid swizzle (contiguous M-slab per XCD -> A-panel L2 reuse).
// PERB: Bt is per-batch [4][Ncols][K], indexed by m0>>12.
// EPI: 0 f32, 1 bf16, 2 bf16+resid, 3 f32 + bias + fused 128-col LN (PatchExpand)
template <int K, int EPI, bool AF32 = false, bool PERB = false>
__global__ __launch_bounds__(256, 2) void gemm_mfma(
    const u16* __restrict__ A, const u16* __restrict__ Bt,
    const float* __restrict__ bias, const u16* __restrict__ resid,
    void* __restrict__ Cout, int nTilesN,
    const float* __restrict__ gup, const float* __restrict__ beup) {
  const int t = threadIdx.x;
  int bid = blockIdx.x;
  const int nwg = gridDim.x;
  if ((nwg & 7) == 0) bid = (bid & 7) * (nwg >> 3) + (bid >> 3);  // bijective
  const int m0 = (bid / nTilesN) * 128;
  const int n0 = (bid % nTilesN) * 128;
  const int Ncols = nTilesN * 128;
  if (PERB) Bt += (size_t)(m0 >> 12) * (size_t)Ncols * K;
  const int lane = t & 63, wid = t >> 6;
  const int wr = wid >> 1, wc = wid & 1;
  const int lrow = lane & 15, kgrp = lane >> 4;

  __shared__ u16 ldsA[2][128 * 32];
  __shared__ u16 ldsB[2][128 * 32];

  int srow[2], sslot[2];
#pragma unroll
  for (int c = 0; c < 2; ++c) {
    int idx = c * 256 + t;
    srow[c] = idx >> 2;
    sslot[c] = (idx & 3) ^ ((srow[c] >> 1) & 3);
  }

  int offA[4], offB[4];
#pragma unroll
  for (int m = 0; m < 4; ++m) {
    int r = wr * 64 + m * 16 + lrow;
    offA[m] = r * 32 + ((kgrp ^ ((r >> 1) & 3)) * 8);
  }
#pragma unroll
  for (int n = 0; n < 4; ++n) {
    int r = wc * 64 + n * 16 + lrow;
    offB[n] = r * 32 + ((kgrp ^ ((r >> 1) & 3)) * 8);
  }

  f32x4 acc[4][4];
#pragma unroll
  for (int m = 0; m < 4; ++m)
#pragma unroll
    for (int n = 0; n < 4; ++n) acc[m][n] = f32x4{0.f, 0.f, 0.f, 0.f};

  auto loadA32 = [&](int c, int kc) -> uint4 {
    const float* A32 = (const float*)A;
    const float* p = A32 + (size_t)(m0 + srow[c]) * K + kc + sslot[c] * 8;
    float4 f0 = *(const float4*)p;
    float4 f1 = *(const float4*)(p + 4);
    u16 o[8] = {f2bf(f0.x), f2bf(f0.y), f2bf(f0.z), f2bf(f0.w),
                f2bf(f1.x), f2bf(f1.y), f2bf(f1.z), f2bf(f1.w)};
    return *(uint4*)o;
  };
  auto stage_async = [&](int buf, int kc) {
#pragma unroll
    for (int c = 0; c < 2; ++c) {
      gload16(A + (size_t)(m0 + srow[c]) * K + kc + sslot[c] * 8,
              &ldsA[buf][(c * 256 + t) * 8]);
      gload16(Bt + (size_t)(n0 + srow[c]) * K + kc + sslot[c] * 8,
              &ldsB[buf][(c * 256 + t) * 8]);
    }
  };

  uint4 ra[2], rb[2];
  if constexpr (AF32) {
#pragma unroll
    for (int c = 0; c < 2; ++c) {
      ra[c] = loadA32(c, 0);
      rb[c] = *(const uint4*)(Bt + (size_t)(n0 + srow[c]) * K + sslot[c] * 8);
    }
#pragma unroll
    for (int c = 0; c < 2; ++c) {
      int idx = c * 256 + t;
      *(uint4*)&ldsA[0][idx * 8] = ra[c];
      *(uint4*)&ldsB[0][idx * 8] = rb[c];
    }
  } else {
    stage_async(0, 0);
  }
  __syncthreads();

  const int nt = K / 32;
  for (int tt = 0; tt < nt; ++tt) {
    const int cur = tt & 1;
    if (tt + 1 < nt) {
      const int kc = (tt + 1) * 32;
      if constexpr (AF32) {
#pragma unroll
        for (int c = 0; c < 2; ++c) {
          ra[c] = loadA32(c, kc);
          rb[c] = *(const uint4*)(Bt + (size_t)(n0 + srow[c]) * K + kc + sslot[c] * 8);
        }
      } else {
        stage_async(cur ^ 1, kc);
      }
    }
    bf16x8 af[4], bf[4];
#pragma unroll
    for (int m = 0; m < 4; ++m) af[m] = *(const bf16x8*)&ldsA[cur][offA[m]];
#pragma unroll
    for (int n = 0; n < 4; ++n) bf[n] = *(const bf16x8*)&ldsB[cur][offB[n]];
#pragma unroll
    for (int m = 0; m < 4; ++m)
#pragma unroll
      for (int n = 0; n < 4; ++n)
        acc[m][n] = __builtin_amdgcn_mfma_f32_16x16x32_bf16(af[m], bf[n], acc[m][n], 0, 0, 0);
    if (AF32 && tt + 1 < nt) {
#pragma unroll
      for (int c = 0; c < 2; ++c) {
        int idx = c * 256 + t;
        *(uint4*)&ldsA[cur ^ 1][idx * 8] = ra[c];
        *(uint4*)&ldsB[cur ^ 1][idx * 8] = rb[c];
      }
    }
    __syncthreads();
  }

  if (EPI == 3) {
    float bcol3[4];
#pragma unroll
    for (int n = 0; n < 4; ++n) {
      int gc = n0 + wc * 64 + n * 16 + lrow;
      bcol3[n] = bias ? bias[gc] : 0.f;
    }
    __shared__ float lnS[2][128], lnQ[2][128];
    float s_[4][4], q_[4][4];
#pragma unroll
    for (int m = 0; m < 4; ++m)
#pragma unroll
      for (int j = 0; j < 4; ++j) {
        float s = 0.f, q = 0.f;
#pragma unroll
        for (int n = 0; n < 4; ++n) {
          float v = acc[m][n][j] + bcol3[n];
          s += v; q += v * v;
        }
        s_[m][j] = s; q_[m][j] = q;
      }
#pragma unroll
    for (int msk = 1; msk < 16; msk <<= 1) {
#pragma unroll
      for (int m = 0; m < 4; ++m)
#pragma unroll
        for (int j = 0; j < 4; ++j) {
          s_[m][j] += __shfl_xor(s_[m][j], msk, 64);
          q_[m][j] += __shfl_xor(q_[m][j], msk, 64);
        }
    }
    if (lrow == 0) {
#pragma unroll
      for (int m = 0; m < 4; ++m)
#pragma unroll
        for (int j = 0; j < 4; ++j) {
          int r = wr * 64 + m * 16 + kgrp * 4 + j;
          lnS[wc][r] = s_[m][j];
          lnQ[wc][r] = q_[m][j];
        }
    }
    __syncthreads();
#pragma unroll
    for (int m = 0; m < 4; ++m) {
      const int rb0 = wr * 64 + m * 16 + kgrp * 4;
#pragma unroll
      for (int j = 0; j < 4; ++j) {
        const int r = rb0 + j;
        float S = lnS[0][r] + lnS[1][r];
        float Q = lnQ[0][r] + lnQ[1][r];
        float mean = S * (1.0f / 128.0f);
        float var = Q * (1.0f / 128.0f) - mean * mean;
        float iv = rsqrtf(var + 1e-5f);
#pragma unroll
        for (int n = 0; n < 4; ++n) {
          int lc = wc * 64 + n * 16 + lrow;
          ((float*)Cout)[(size_t)(m0 + r) * Ncols + n0 + lc] =
              (acc[m][n][j] + bcol3[n] - mean) * iv * gup[lc] + beup[lc];
        }
      }
    }
    return;
  }

  float bcol[4];
#pragma unroll
  for (int n = 0; n < 4; ++n) {
    int col = n0 + wc * 64 + n * 16 + (lane & 15);
    bcol[n] = bias ? bias[col] : 0.f;
  }
#pragma unroll
  for (int m = 0; m < 4; ++m) {
    const int r0 = m0 + wr * 64 + m * 16 + kgrp * 4;
#pragma unroll
    for (int n = 0; n < 4; ++n) {
      const int col = n0 + wc * 64 + n * 16 + (lane & 15);
#pragma unroll
      for (int j = 0; j < 4; ++j) {
        float v = acc[m][n][j] + bcol[n];
        size_t idx = (size_t)(r0 + j) * Ncols + col;
        if (EPI == 0) {
          ((float*)Cout)[idx] = v;
        } else if (EPI == 1) {
          ((u16*)Cout)[idx] = f2bf(v);
        } else {
          v += bf2f(resid[idx]);
          ((u16*)Cout)[idx] = f2bf(v);
        }
      }
    }
  }
}

// ------- ln256_both: blocks [0,ROWS): n1T = LN(x1e); [ROWS,2R): LN(x2) -> n2T + qmat -------
// qmat = per-head (32-ch) softmax of LN(x2) row — replaces k5's q computation.
__global__ __launch_bounds__(256) void ln256_both(
    const u16* __restrict__ x1e_b, const float* __restrict__ x2,
    const float* __restrict__ g, const float* __restrict__ be,
    u16* __restrict__ n1T, u16* __restrict__ n2T, u16* __restrict__ qmat) {
  int row = blockIdx.x;
  const int t = threadIdx.x;
  const bool first = row < ROWS;
  if (!first) row -= ROWS;
  __shared__ float ws[8];
  float v = first ? bf2f(x1e_b[(size_t)row * DD + t])
                  : x2[(size_t)row * DD + t];
  float s = v, q = v * v;
#pragma unroll
  for (int m = 1; m < 64; m <<= 1) {
    s += __shfl_xor(s, m, 64);
    q += __shfl_xor(q, m, 64);
  }
  if ((t & 63) == 0) { ws[t >> 6] = s; ws[4 + (t >> 6)] = q; }
  __syncthreads();
  s = ws[0] + ws[1] + ws[2] + ws[3];
  q = ws[4] + ws[5] + ws[6] + ws[7];
  float mean = s * (1.0f / DD);
  float var = q * (1.0f / DD) - mean * mean;
  float iv = rsqrtf(var + 1e-5f);
  u16 rb = f2bf((v - mean) * iv * g[t] + be[t]);
  int b = row >> 12, n = row & 4095;
  if (first) {
    n1T[((size_t)(b * 256 + t)) * 4096 + n] = rb;
  } else {
    n2T[((size_t)(b * 256 + t)) * 4096 + n] = rb;
    float vq = bf2f(rb);
    float hm = vq;
#pragma unroll
    for (int m = 1; m < 32; m <<= 1) hm = fmaxf(hm, __shfl_xor(hm, m, 32));
    float he = __expf(vq - hm);
    float hs = he;
#pragma unroll
    for (int m = 1; m < 32; m <<= 1) hs += __shfl_xor(hs, m, 32);
    qmat[(size_t)row * DD + t] = f2bf(he / hs);
  }
}

// ------- k34: fused column-softmax stats + ctx, coalesced via n2T/n1T -------
__global__ __launch_bounds__(256) void k34_ctx(
    const u16* __restrict__ n2T, const u16* __restrict__ n1T,
    float* __restrict__ ctx) {
  const int bid = blockIdx.x;
  const int bx = (bid & 7) * 128 + (bid >> 3);  // bijective, 1024%8==0
  const int b = bx >> 8, d = bx & 255;
  const int h = d >> 5, kk = d & 31;
  const int t = threadIdx.x;
  __shared__ u16 prow[4096];
  __shared__ float xred[8];
  __shared__ float sw[128];
  const u16* src = n2T + (size_t)bx * 4096;
  ((uint4*)prow)[t] = ((const uint4*)src)[t];
  ((uint4*)prow)[256 + t] = ((const uint4*)src)[256 + t];
  __syncthreads();
  float mx = -1e30f;
#pragma unroll
  for (int i = 0; i < 16; ++i) mx = fmaxf(mx, bf2f(prow[i * 256 + t]));
#pragma unroll
  for (int m = 1; m < 64; m <<= 1) mx = fmaxf(mx, __shfl_xor(mx, m, 64));
  if ((t & 63) == 0) xred[t >> 6] = mx;
  __syncthreads();
  mx = fmaxf(fmaxf(xred[0], xred[1]), fmaxf(xred[2], xred[3]));
  float sme = 0.f;
#pragma unroll
  for (int i = 0; i < 16; ++i) sme += __expf(bf2f(prow[i * 256 + t]) - mx);
#pragma unroll
  for (int m = 1; m < 64; m <<= 1) sme += __shfl_xor(sme, m, 64);
  if ((t & 63) == 0) xred[4 + (t >> 6)] = sme;
  __syncthreads();
  const float inv = 1.0f / (xred[4] + xred[5] + xred[6] + xred[7]);

  float acc[32];
#pragma unroll
  for (int v = 0; v < 32; ++v) acc[v] = 0.f;
  const u16* vbase = n1T + ((size_t)(b * 256 + h * 32)) * 4096;
  for (int i = 0; i < 16; ++i) {
    const int n = i * 256 + t;
    const float p = __expf(bf2f(prow[n]) - mx) * inv;
#pragma unroll
    for (int v = 0; v < 32; ++v)
      acc[v] += p * bf2f(vbase[(size_t)v * 4096 + n]);
  }
#pragma unroll
  for (int v = 0; v < 32; ++v) {
#pragma unroll
    for (int m = 1; m < 64; m <<= 1) acc[v] += __shfl_xor(acc[v], m, 64);
  }
  if ((t & 63) == 0) {
#pragma unroll
    for (int v = 0; v < 32; ++v) sw[(t >> 6) * 32 + v] = acc[v];
  }
  __syncthreads();
  if (t < 32)
    ctx[(((size_t)(b * 8 + h)) * 32 + kk) * 32 + t] =
        sw[t] + sw[32 + t] + sw[64 + t] + sw[96 + t];
}

// ------- m2_build: M2T[b][e][h*32+kk] = sum_v ctx[b][h][kk][v] * w_rep[h*32+v][e] -------
// grid = 4b x 16 e-chunks; 256 threads = 32 e x 8 h; ctx[b] (32KB) in LDS.
__global__ __launch_bounds__(256) void m2_build(
    const float* __restrict__ ctx, const u16* __restrict__ w_rept,
    u16* __restrict__ m2t) {
  const int b = blockIdx.x >> 4, ec = blockIdx.x & 15;
  const int t = threadIdx.x;
  const int e = ec * 32 + (t >> 3), h = t & 7;
  __shared__ float cl[8192];
#pragma unroll
  for (int i = 0; i < 8; ++i)
    *(float4*)(cl + t * 32 + i * 4) = *(const float4*)(ctx + b * 8192 + t * 32 + i * 4);
  __syncthreads();
  float wf[32];
  {
    u16 wv[32];
#pragma unroll
    for (int i = 0; i < 4; ++i)
      *(uint4*)(wv + i * 8) = *(const uint4*)(w_rept + (size_t)e * 256 + h * 32 + i * 8);
#pragma unroll
    for (int v = 0; v < 32; ++v) wf[v] = bf2f(wv[v]);
  }
  u16 outv[32];
#pragma unroll
  for (int kk = 0; kk < 32; ++kk) {
    float acc = 0.f;
    const float* cp = cl + h * 1024 + kk * 32;
#pragma unroll
    for (int v = 0; v < 32; ++v) acc += cp[v] * wf[v];
    outv[kk] = f2bf(acc);
  }
  u16* dst = m2t + ((size_t)(b * 512 + e)) * 256 + h * 32;
#pragma unroll
  for (int i = 0; i < 4; ++i) *(uint4*)(dst + i * 8) = *(uint4*)(outv + i * 8);
}

// ------- l3: rep = LN(rep_b); tx = concat(x1e,x2)+rep; txln = LN(tx) -------
__global__ __launch_bounds__(256) void l3_reptx(
    const u16* __restrict__ rep_b, const u16* __restrict__ x1e,
    const float* __restrict__ x2,
    const float* __restrict__ g_an, const float* __restrict__ be_an,
    const float* __restrict__ g_n2, const float* __restrict__ be_n2,
    u16* __restrict__ tx, u16* __restrict__ txln) {
  const int row = blockIdx.x, t = threadIdx.x;
  __shared__ float ws[8];
  float a0 = bf2f(rep_b[(size_t)row * DD2 + t]);
  float a1 = bf2f(rep_b[(size_t)row * DD2 + 256 + t]);
  float s = a0 + a1, q = a0 * a0 + a1 * a1;
#pragma unroll
  for (int m = 1; m < 64; m <<= 1) {
    s += __shfl_xor(s, m, 64);
    q += __shfl_xor(q, m, 64);
  }
  if ((t & 63) == 0) { ws[t >> 6] = s; ws[4 + (t >> 6)] = q; }
  __syncthreads();
  s = ws[0] + ws[1] + ws[2] + ws[3];
  q = ws[4] + ws[5] + ws[6] + ws[7];
  float mean = s * (1.0f / DD2);
  float var = q * (1.0f / DD2) - mean * mean;
  float iv = rsqrtf(var + 1e-5f);
  float r0 = (a0 - mean) * iv * g_an[t] + be_an[t];
  float r1 = (a1 - mean) * iv * g_an[256 + t] + be_an[256 + t];
  float t0 = bf2f(x1e[(size_t)row * DD + t]) + r0;
  float t1 = x2[(size_t)row * DD + t] + r1;
  tx[(size_t)row * DD2 + t] = f2bf(t0);
  tx[(size_t)row * DD2 + 256 + t] = f2bf(t1);
  __syncthreads();
  s = t0 + t1; q = t0 * t0 + t1 * t1;
#pragma unroll
  for (int m = 1; m < 64; m <<= 1) {
    s += __shfl_xor(s, m, 64);
    q += __shfl_xor(q, m, 64);
  }
  if ((t & 63) == 0) { ws[t >> 6] = s; ws[4 + (t >> 6)] = q; }
  __syncthreads();
  s = ws[0] + ws[1] + ws[2] + ws[3];
  q = ws[4] + ws[5] + ws[6] + ws[7];
  mean = s * (1.0f / DD2);
  var = q * (1.0f / DD2) - mean * mean;
  iv = rsqrtf(var + 1e-5f);
  txln[(size_t)row * DD2 + t] = f2bf((t0 - mean) * iv * g_n2[t] + be_n2[t]);
  txln[(size_t)row * DD2 + 256 + t] = f2bf((t1 - mean) * iv * g_n2[256 + t] + be_n2[256 + t]);
}

// ------- c8a_col: z-column dw-conv3d + skip + LN + GELU (~74us practical floor) -------
__global__ __launch_bounds__(1024) void c8a_col(
    const u16* __restrict__ h, const float* __restrict__ w_dwt,
    const float* __restrict__ b_dw, const float* __restrict__ g,
    const float* __restrict__ be, u16* __restrict__ ax) {
  const int bid = blockIdx.x;
  const int cidx = (bid & 7) * 128 + (bid >> 3);
  const int b = cidx >> 8, y = (cidx >> 4) & 15, x = cidx & 15;
  const int t = threadIdx.x;
  const int lane = t & 63, wave = t >> 6;
  const size_t hb = (size_t)b * NN * CC2;

  __shared__ float2 red[16][16];
  __shared__ float2 stats[16];

  int coln[9];
  float cmask[9];
#pragma unroll
  for (int dy = -1; dy <= 1; ++dy)
#pragma unroll
    for (int dx = -1; dx <= 1; ++dx) {
      int qq = (dy + 1) * 3 + (dx + 1);
      int yy = y + dy, xx = x + dx;
      bool ok = ((unsigned)yy < 16u) && ((unsigned)xx < 16u);
      coln[qq] = ((ok ? yy : y) << 4) | (ok ? xx : x);
      cmask[qq] = ok ? 1.f : 0.f;
    }

  float wr[3][9];
#pragma unroll
  for (int p = 0; p < 3; ++p)
#pragma unroll
    for (int qq = 0; qq < 9; ++qq)
      wr[p][qq] = w_dwt[(p * 9 + qq) * CC2 + t] * cmask[qq];
  const float bias = b_dw[t];

  u16 win[3][9];
#define LOADPLANE(ZL, SLOT)                                                   \
  do {                                                                        \
    if ((ZL) >= 0 && (ZL) < 16) {                                             \
      _Pragma("unroll") for (int qq = 0; qq < 9; ++qq) win[SLOT][qq] =        \
          h[hb + (size_t)((((ZL) << 8) | coln[qq])) * CC2 + t];               \
    } else {                                                                  \
      _Pragma("unroll") for (int qq = 0; qq < 9; ++qq) win[SLOT][qq] = 0;     \
    }                                                                         \
  } while (0)

  LOADPLANE(-1, 0);
  LOADPLANE(0, 1);
  LOADPLANE(1, 2);

  float vs[16];
#pragma unroll
  for (int z = 0; z < 16; ++z) {
    const int pm1 = z % 3, pz = (z + 1) % 3, pp1 = (z + 2) % 3;
    float a0 = bias;
#pragma unroll
    for (int qq = 0; qq < 9; ++qq) {
      a0 += bf2f(win[pm1][qq]) * wr[0][qq];
      a0 += bf2f(win[pz][qq]) * wr[1][qq];
      a0 += bf2f(win[pp1][qq]) * wr[2][qq];
    }
    float v = a0 + bf2f(win[pz][4]);
    LOADPLANE(z + 2, pm1);
    vs[z] = v;
    float s = v, q2 = v * v;
#pragma unroll
    for (int m = 1; m < 64; m <<= 1) {
      s += __shfl_xor(s, m, 64);
      q2 += __shfl_xor(q2, m, 64);
    }
    if (lane == 0) red[z][wave] = make_float2(s, q2);
  }
#undef LOADPLANE
  __syncthreads();

  {
    const int z = wave;
    float S = (lane < 16) ? red[z][lane].x : 0.f;
    float Q = (lane < 16) ? red[z][lane].y : 0.f;
#pragma unroll
    for (int m = 1; m < 16; m <<= 1) {
      S += __shfl_xor(S, m, 64);
      Q += __shfl_xor(Q, m, 64);
    }
    if (lane == 0) {
      float mean = S * (1.0f / CC2);
      float var = Q * (1.0f / CC2) - mean * mean;
      stats[z] = make_float2(mean, rsqrtf(var + 1e-5f));
    }
  }
  __syncthreads();

  const float gg = g[t], bb = be[t];
#pragma unroll
  for (int z = 0; z < 16; ++z) {
    float2 st = stats[z];
    float u = (vs[z] - st.x) * st.y * gg + bb;
    float s2 = 1.5957691216f * (u + 0.044715f * u * u * u);
    float o = u / (1.0f + __expf(-s2));
    ax[((size_t)(b * NN + ((z << 8) | (y << 4) | x))) * CC2 + t] = f2bf(o);
  }
}

extern "C" void kernel_launch(void* const* d_in, const int* in_sizes, int n_in,
                              void* d_out, int out_size, void* d_ws, size_t ws_size,
                              hipStream_t stream) {
  const float* x1    = (const float*)d_in[0];
  const float* x2    = (const float*)d_in[1];
  const float* w_x1  = (const float*)d_in[2];
  const float* b_x1  = (const float*)d_in[3];
  const float* g_n1  = (const float*)d_in[4];
  const float* be_n1 = (const float*)d_in[5];
  const float* w_rep = (const float*)d_in[6];
  const float* b_rep = (const float*)d_in[7];
  const float* g_an  = (const float*)d_in[8];
  const float* be_an = (const float*)d_in[9];
  const float* g_n2  = (const float*)d_in[10];
  const float* be_n2 = (const float*)d_in[11];
  const float* w_fc1 = (const float*)d_in[12];
  const float* b_fc1 = (const float*)d_in[13];
  const float* w_dw  = (const float*)d_in[14];
  const float* b_dw  = (const float*)d_in[15];
  const float* g_m1  = (const float*)d_in[16];
  const float* be_m1 = (const float*)d_in[17];
  const float* w_fc2 = (const float*)d_in[18];
  const float* b_fc2 = (const float*)d_in[19];
  const float* w_cat = (const float*)d_in[20];
  const float* b_cat = (const float*)d_in[21];
  const float* w_exp = (const float*)d_in[22];
  const float* g_up  = (const float*)d_in[23];
  const float* be_up = (const float*)d_in[24];

  char* ws = (char*)d_ws;
  float* out = (float*)d_out;

  u16*   qmat    = (u16*)(ws + 0);          // 8MB
  u16*   x1e_b   = (u16*)(ws + 8 * MB);     // bf16 x1e; then mx
  u16*   n1T     = (u16*)(ws + 24 * MB);
  u16*   n2T     = (u16*)(ws + 40 * MB);
  float* ctx     = (float*)(ws + 48 * MB);
  u16*   rep_b   = (u16*)(ws + 49 * MB);    // bf16 rep; then ax
  u16*   tx      = (u16*)(ws + 81 * MB);
  u16*   txln    = (u16*)(ws + 97 * MB);
  u16*   hbuf    = (u16*)(ws + 113 * MB);
  u16*   ax      = (u16*)(ws + 49 * MB);
  u16*   mx      = (u16*)(ws + 8 * MB);
  u16*   w_x1t   = (u16*)(ws + 145 * MB);
  u16*   w_rept  = w_x1t + 256 * 256;
  u16*   w_fc1t  = w_rept + 512 * 256;
  u16*   w_fc2t  = w_fc1t + 1024 * 512;
  u16*   w_cat_b = w_fc2t + 512 * 1024;     // [512][256] bf16 (Bt for wcomb)
  u16*   w_expt  = w_cat_b + 512 * 256;     // [1024][256] bf16
  float* w_dwt   = (float*)(ws + 149 * MB);
  u16*   w_combT = (u16*)(ws + 150 * MB);   // [1024][512] bf16
  float* b_comb  = (float*)(ws + 151 * MB); // [1024] fp32
  u16*   m2t     = (u16*)(ws + 152 * MB);   // [4][512][256] bf16

  wprep_all<<<(1667072 + 255) / 256, 256, 0, stream>>>(
      w_x1, w_rep, w_fc1, w_fc2, w_cat, w_exp, w_dw, b_cat,
      w_x1t, w_rept, w_fc1t, w_fc2t, w_cat_b, w_expt, w_dwt, b_comb);

  // w_combT = w_exp^T @ w_cat^T  ([1024][512] bf16, Bt-layout for final GEMM)
  gemm_mfma<256, 1><<<32, 256, 0, stream>>>(
      w_expt, w_cat_b, nullptr, nullptr, w_combT, 4, nullptr, nullptr);

  gemm_mfma<256, 1, true><<<(ROWS / 128) * 2, 256, 0, stream>>>(
      (const u16*)x1, w_x1t, b_x1, nullptr, x1e_b, 2, nullptr, nullptr);
  ln256_both<<<2 * ROWS, 256, 0, stream>>>(x1e_b, x2, g_n1, be_n1, n1T, n2T, qmat);
  k34_ctx<<<BB * 256, 256, 0, stream>>>(n2T, n1T, ctx);
  m2_build<<<64, 256, 0, stream>>>(ctx, w_rept, m2t);
  // rep = qmat @ M2[b] + b_rep   (replaces k5 + old g2)
  gemm_mfma<256, 1, false, true><<<(ROWS / 128) * 4, 256, 0, stream>>>(
      qmat, m2t, b_rep, nullptr, rep_b, 4, nullptr, nullptr);
  l3_reptx<<<ROWS, 256, 0, stream>>>(rep_b, x1e_b, x2, g_an, be_an, g_n2, be_n2, tx, txln);
  gemm_mfma<512, 1><<<(ROWS / 128) * 8, 256, 0, stream>>>(
      txln, w_fc1t, b_fc1, nullptr, hbuf, 8, nullptr, nullptr);
  c8a_col<<<1024, 1024, 0, stream>>>(hbuf, w_dwt, b_dw, g_m1, be_m1, ax);
  gemm_mfma<1024, 2><<<(ROWS / 128) * 4, 256, 0, stream>>>(
      ax, w_fc2t, b_fc2, tx, mx, 4, nullptr, nullptr);
  // merged cat+expand: out = LN128( mx @ w_comb + b_comb )
  gemm_mfma<512, 3><<<(ROWS / 128) * 8, 256, 0, stream>>>(
      mx, w_combT, b_comb, nullptr, out, 8, g_up, be_up);
}

// Round 12
// 300.739 us; speedup vs baseline: 1.0903x; 1.0903x over previous
//
#include <hip/hip_runtime.h>
#include <math.h>

using u16 = unsigned short;
typedef __bf16 bf16x8 __attribute__((ext_vector_type(8)));
typedef _Float16 h16x8 __attribute__((ext_vector_type(8)));
typedef _Float16 h2 __attribute__((ext_vector_type(2)));
typedef float f32x4 __attribute__((ext_vector_type(4)));

#define BB 4
#define NN 4096
#define DD 256
#define DD2 512
#define CC2 1024
static constexpr int ROWS = BB * NN;  // 16384
static constexpr size_t MB = 1024 * 1024;

__device__ __forceinline__ u16 f2bf(float f) {
  union { float f; unsigned u; } v; v.f = f;
  unsigned r = v.u + 0x7fffu + ((v.u >> 16) & 1u);
  return (u16)(r >> 16);
}
__device__ __forceinline__ float bf2f(u16 u) {
  union { unsigned u; float f; } v; v.u = ((unsigned)u) << 16;
  return v.f;
}
__device__ __forceinline__ u16 f2h(float f) {
  union { _Float16 h; u16 u; } v; v.h = (_Float16)f; return v.u;
}
__device__ __forceinline__ void gload16(const void* g, void* l) {
  __builtin_amdgcn_global_load_lds(
      (const __attribute__((address_space(1))) void*)g,
      (__attribute__((address_space(3))) void*)l, 16, 0, 0);
}

// ---------------- one-shot weight prep ----------------
// w_x1t | w_rept | w_fc1t | w_fc2h(fp16) | w_catt | w_expt | w_dwh(packed fp16)
__global__ __launch_bounds__(256) void wprep_all(
    const float* __restrict__ w_x1, const float* __restrict__ w_rep,
    const float* __restrict__ w_fc1, const float* __restrict__ w_fc2,
    const float* __restrict__ w_cat, const float* __restrict__ w_exp,
    const float* __restrict__ w_dw,
    u16* __restrict__ w_x1t, u16* __restrict__ w_rept,
    u16* __restrict__ w_fc1t, u16* __restrict__ w_fc2h,
    u16* __restrict__ w_catt, u16* __restrict__ w_expt,
    unsigned* __restrict__ w_dwh) {
  int i = blockIdx.x * 256 + threadIdx.x;
  if (i < 65536) { int n = i >> 8, k = i & 255; w_x1t[i] = f2bf(w_x1[k * 256 + n]); return; }
  i -= 65536;
  if (i < 131072) { int n = i >> 8, k = i & 255; w_rept[i] = f2bf(w_rep[k * 512 + n]); return; }
  i -= 131072;
  if (i < 524288) { int n = i >> 9, k = i & 511; w_fc1t[i] = f2bf(w_fc1[k * 1024 + n]); return; }
  i -= 524288;
  if (i < 524288) { int n = i >> 10, k = i & 1023; w_fc2h[i] = f2h(w_fc2[k * 512 + n]); return; }
  i -= 524288;
  if (i < 131072) { int n = i >> 9, k = i & 511; w_catt[i] = f2bf(w_cat[k * 256 + n]); return; }
  i -= 131072;
  if (i < 262144) { int n = i >> 8, k = i & 255; w_expt[i] = f2bf(w_exp[k * 1024 + n]); return; }
  i -= 262144;
  if (i < 13824) {
    int tap = i >> 9, cp = i & 511;
    unsigned lo = f2h(w_dw[(2 * cp) * 27 + tap]);
    unsigned hi = f2h(w_dw[(2 * cp + 1) * 27 + tap]);
    w_dwh[i] = lo | (hi << 16);
  }
}

// ---------------- generic 128x128-tile MFMA GEMM ----------------
// A [M][K], Bt [N][K], C row-major [M][Ncols]
// AF32: A is fp32, converted in-register. PERB: Bt is per-batch [4][Ncols][K].
// F16: A/B fragments are fp16 (mfma_f32_16x16x32_f16) instead of bf16.
// EPI: 0 f32 | 1 bf16 | 2 bf16 + bf16-resid | 3 f32 + bias + fused 128-col LN | 4 fp16
template <int K, int EPI, bool AF32 = false, bool PERB = false, bool F16 = false>
__global__ __launch_bounds__(256, 2) void gemm_mfma(
    const u16* __restrict__ A, const u16* __restrict__ Bt,
    const float* __restrict__ bias, const u16* __restrict__ resid,
    void* __restrict__ Cout, int nTilesN,
    const float* __restrict__ gup, const float* __restrict__ beup) {
  const int t = threadIdx.x;
  const int bid = blockIdx.x;
  const int m0 = (bid / nTilesN) * 128;
  const int n0 = (bid % nTilesN) * 128;
  const int Ncols = nTilesN * 128;
  if (PERB) Bt += (size_t)(m0 >> 12) * (size_t)Ncols * K;
  const int lane = t & 63, wid = t >> 6;
  const int wr = wid >> 1, wc = wid & 1;
  const int lrow = lane & 15, kgrp = lane >> 4;

  __shared__ u16 ldsA[2][128 * 32];
  __shared__ u16 ldsB[2][128 * 32];

  int srow[2], sslot[2];
#pragma unroll
  for (int c = 0; c < 2; ++c) {
    int idx = c * 256 + t;
    srow[c] = idx >> 2;
    sslot[c] = (idx & 3) ^ ((srow[c] >> 1) & 3);
  }

  int offA[4], offB[4];
#pragma unroll
  for (int m = 0; m < 4; ++m) {
    int r = wr * 64 + m * 16 + lrow;
    offA[m] = r * 32 + ((kgrp ^ ((r >> 1) & 3)) * 8);
  }
#pragma unroll
  for (int n = 0; n < 4; ++n) {
    int r = wc * 64 + n * 16 + lrow;
    offB[n] = r * 32 + ((kgrp ^ ((r >> 1) & 3)) * 8);
  }

  f32x4 acc[4][4];
#pragma unroll
  for (int m = 0; m < 4; ++m)
#pragma unroll
    for (int n = 0; n < 4; ++n) acc[m][n] = f32x4{0.f, 0.f, 0.f, 0.f};

  auto loadA32 = [&](int c, int kc) -> uint4 {
    const float* A32 = (const float*)A;
    const float* p = A32 + (size_t)(m0 + srow[c]) * K + kc + sslot[c] * 8;
    float4 f0 = *(const float4*)p;
    float4 f1 = *(const float4*)(p + 4);
    u16 o[8] = {f2bf(f0.x), f2bf(f0.y), f2bf(f0.z), f2bf(f0.w),
                f2bf(f1.x), f2bf(f1.y), f2bf(f1.z), f2bf(f1.w)};
    return *(uint4*)o;
  };
  auto stage_async = [&](int buf, int kc) {
#pragma unroll
    for (int c = 0; c < 2; ++c) {
      gload16(A + (size_t)(m0 + srow[c]) * K + kc + sslot[c] * 8,
              &ldsA[buf][(c * 256 + t) * 8]);
      gload16(Bt + (size_t)(n0 + srow[c]) * K + kc + sslot[c] * 8,
              &ldsB[buf][(c * 256 + t) * 8]);
    }
  };

  uint4 ra[2], rb[2];
  if constexpr (AF32) {
#pragma unroll
    for (int c = 0; c < 2; ++c) {
      ra[c] = loadA32(c, 0);
      rb[c] = *(const uint4*)(Bt + (size_t)(n0 + srow[c]) * K + sslot[c] * 8);
    }
#pragma unroll
    for (int c = 0; c < 2; ++c) {
      int idx = c * 256 + t;
      *(uint4*)&ldsA[0][idx * 8] = ra[c];
      *(uint4*)&ldsB[0][idx * 8] = rb[c];
    }
  } else {
    stage_async(0, 0);
  }
  __syncthreads();

  const int nt = K / 32;
  for (int tt = 0; tt < nt; ++tt) {
    const int cur = tt & 1;
    if (tt + 1 < nt) {
      const int kc = (tt + 1) * 32;
      if constexpr (AF32) {
#pragma unroll
        for (int c = 0; c < 2; ++c) {
          ra[c] = loadA32(c, kc);
          rb[c] = *(const uint4*)(Bt + (size_t)(n0 + srow[c]) * K + kc + sslot[c] * 8);
        }
      } else {
        stage_async(cur ^ 1, kc);
      }
    }
    if constexpr (F16) {
      h16x8 af[4], bf[4];
#pragma unroll
      for (int m = 0; m < 4; ++m) af[m] = *(const h16x8*)&ldsA[cur][offA[m]];
#pragma unroll
      for (int n = 0; n < 4; ++n) bf[n] = *(const h16x8*)&ldsB[cur][offB[n]];
#pragma unroll
      for (int m = 0; m < 4; ++m)
#pragma unroll
        for (int n = 0; n < 4; ++n)
          acc[m][n] = __builtin_amdgcn_mfma_f32_16x16x32_f16(af[m], bf[n], acc[m][n], 0, 0, 0);
    } else {
      bf16x8 af[4], bf[4];
#pragma unroll
      for (int m = 0; m < 4; ++m) af[m] = *(const bf16x8*)&ldsA[cur][offA[m]];
#pragma unroll
      for (int n = 0; n < 4; ++n) bf[n] = *(const bf16x8*)&ldsB[cur][offB[n]];
#pragma unroll
      for (int m = 0; m < 4; ++m)
#pragma unroll
        for (int n = 0; n < 4; ++n)
          acc[m][n] = __builtin_amdgcn_mfma_f32_16x16x32_bf16(af[m], bf[n], acc[m][n], 0, 0, 0);
    }
    if (AF32 && tt + 1 < nt) {
#pragma unroll
      for (int c = 0; c < 2; ++c) {
        int idx = c * 256 + t;
        *(uint4*)&ldsA[cur ^ 1][idx * 8] = ra[c];
        *(uint4*)&ldsB[cur ^ 1][idx * 8] = rb[c];
      }
    }
    __syncthreads();
  }

  if (EPI == 3) {
    __shared__ float lnS[2][128], lnQ[2][128];
    float s_[4][4], q_[4][4];
#pragma unroll
    for (int m = 0; m < 4; ++m)
#pragma unroll
      for (int j = 0; j < 4; ++j) {
        float s = 0.f, q = 0.f;
#pragma unroll
        for (int n = 0; n < 4; ++n) {
          float v = acc[m][n][j];
          s += v; q += v * v;
        }
        s_[m][j] = s; q_[m][j] = q;
      }
#pragma unroll
    for (int msk = 1; msk < 16; msk <<= 1) {
#pragma unroll
      for (int m = 0; m < 4; ++m)
#pragma unroll
        for (int j = 0; j < 4; ++j) {
          s_[m][j] += __shfl_xor(s_[m][j], msk, 64);
          q_[m][j] += __shfl_xor(q_[m][j], msk, 64);
        }
    }
    if (lrow == 0) {
#pragma unroll
      for (int m = 0; m < 4; ++m)
#pragma unroll
        for (int j = 0; j < 4; ++j) {
          int r = wr * 64 + m * 16 + kgrp * 4 + j;
          lnS[wc][r] = s_[m][j];
          lnQ[wc][r] = q_[m][j];
        }
    }
    __syncthreads();
#pragma unroll
    for (int m = 0; m < 4; ++m) {
      const int rb0 = wr * 64 + m * 16 + kgrp * 4;
#pragma unroll
      for (int j = 0; j < 4; ++j) {
        const int r = rb0 + j;
        float S = lnS[0][r] + lnS[1][r];
        float Q = lnQ[0][r] + lnQ[1][r];
        float mean = S * (1.0f / 128.0f);
        float var = Q * (1.0f / 128.0f) - mean * mean;
        float iv = rsqrtf(var + 1e-5f);
#pragma unroll
        for (int n = 0; n < 4; ++n) {
          int lc = wc * 64 + n * 16 + lrow;
          ((float*)Cout)[(size_t)(m0 + r) * Ncols + n0 + lc] =
              (acc[m][n][j] - mean) * iv * gup[lc] + beup[lc];
        }
      }
    }
    return;
  }

  float bcol[4];
#pragma unroll
  for (int n = 0; n < 4; ++n) {
    int col = n0 + wc * 64 + n * 16 + (lane & 15);
    bcol[n] = bias ? bias[col] : 0.f;
  }
#pragma unroll
  for (int m = 0; m < 4; ++m) {
    const int r0 = m0 + wr * 64 + m * 16 + kgrp * 4;
#pragma unroll
    for (int n = 0; n < 4; ++n) {
      const int col = n0 + wc * 64 + n * 16 + (lane & 15);
#pragma unroll
      for (int j = 0; j < 4; ++j) {
        float v = acc[m][n][j] + bcol[n];
        size_t idx = (size_t)(r0 + j) * Ncols + col;
        if (EPI == 0) {
          ((float*)Cout)[idx] = v;
        } else if (EPI == 1) {
          ((u16*)Cout)[idx] = f2bf(v);
        } else if (EPI == 4) {
          ((u16*)Cout)[idx] = f2h(v);
        } else {
          v += bf2f(resid[idx]);
          ((u16*)Cout)[idx] = f2bf(v);
        }
      }
    }
  }
}

// ------- ln256_both: [0,ROWS): n1T = LN(x1e); [ROWS,2R): LN(x2) -> n2T + qmat -------
__global__ __launch_bounds__(256) void ln256_both(
    const u16* __restrict__ x1e_b, const float* __restrict__ x2,
    const float* __restrict__ g, const float* __restrict__ be,
    u16* __restrict__ n1T, u16* __restrict__ n2T, u16* __restrict__ qmat) {
  int row = blockIdx.x;
  const int t = threadIdx.x;
  const bool first = row < ROWS;
  if (!first) row -= ROWS;
  __shared__ float ws[8];
  float v = first ? bf2f(x1e_b[(size_t)row * DD + t])
                  : x2[(size_t)row * DD + t];
  float s = v, q = v * v;
#pragma unroll
  for (int m = 1; m < 64; m <<= 1) {
    s += __shfl_xor(s, m, 64);
    q += __shfl_xor(q, m, 64);
  }
  if ((t & 63) == 0) { ws[t >> 6] = s; ws[4 + (t >> 6)] = q; }
  __syncthreads();
  s = ws[0] + ws[1] + ws[2] + ws[3];
  q = ws[4] + ws[5] + ws[6] + ws[7];
  float mean = s * (1.0f / DD);
  float var = q * (1.0f / DD) - mean * mean;
  float iv = rsqrtf(var + 1e-5f);
  u16 rb = f2bf((v - mean) * iv * g[t] + be[t]);
  int b = row >> 12, n = row & 4095;
  if (first) {
    n1T[((size_t)(b * 256 + t)) * 4096 + n] = rb;
  } else {
    n2T[((size_t)(b * 256 + t)) * 4096 + n] = rb;
    float vq = bf2f(rb);
    float hm = vq;
#pragma unroll
    for (int m = 1; m < 32; m <<= 1) hm = fmaxf(hm, __shfl_xor(hm, m, 32));
    float he = __expf(vq - hm);
    float hs = he;
#pragma unroll
    for (int m = 1; m < 32; m <<= 1) hs += __shfl_xor(hs, m, 32);
    qmat[(size_t)row * DD + t] = f2bf(he / hs);
  }
}

// ------- k34: fused column-softmax stats + ctx, coalesced via n2T/n1T -------
__global__ __launch_bounds__(256) void k34_ctx(
    const u16* __restrict__ n2T, const u16* __restrict__ n1T,
    float* __restrict__ ctx) {
  const int bid = blockIdx.x;
  const int bx = (bid & 7) * 128 + (bid >> 3);  // bijective, 1024%8==0
  const int b = bx >> 8, d = bx & 255;
  const int h = d >> 5, kk = d & 31;
  const int t = threadIdx.x;
  __shared__ u16 prow[4096];
  __shared__ float xred[8];
  __shared__ float sw[128];
  const u16* src = n2T + (size_t)bx * 4096;
  ((uint4*)prow)[t] = ((const uint4*)src)[t];
  ((uint4*)prow)[256 + t] = ((const uint4*)src)[256 + t];
  __syncthreads();
  float mx = -1e30f;
#pragma unroll
  for (int i = 0; i < 16; ++i) mx = fmaxf(mx, bf2f(prow[i * 256 + t]));
#pragma unroll
  for (int m = 1; m < 64; m <<= 1) mx = fmaxf(mx, __shfl_xor(mx, m, 64));
  if ((t & 63) == 0) xred[t >> 6] = mx;
  __syncthreads();
  mx = fmaxf(fmaxf(xred[0], xred[1]), fmaxf(xred[2], xred[3]));
  float sme = 0.f;
#pragma unroll
  for (int i = 0; i < 16; ++i) sme += __expf(bf2f(prow[i * 256 + t]) - mx);
#pragma unroll
  for (int m = 1; m < 64; m <<= 1) sme += __shfl_xor(sme, m, 64);
  if ((t & 63) == 0) xred[4 + (t >> 6)] = sme;
  __syncthreads();
  const float inv = 1.0f / (xred[4] + xred[5] + xred[6] + xred[7]);

  float acc[32];
#pragma unroll
  for (int v = 0; v < 32; ++v) acc[v] = 0.f;
  const u16* vbase = n1T + ((size_t)(b * 256 + h * 32)) * 4096;
  for (int i = 0; i < 16; ++i) {
    const int n = i * 256 + t;
    const float p = __expf(bf2f(prow[n]) - mx) * inv;
#pragma unroll
    for (int v = 0; v < 32; ++v)
      acc[v] += p * bf2f(vbase[(size_t)v * 4096 + n]);
  }
#pragma unroll
  for (int v = 0; v < 32; ++v) {
#pragma unroll
    for (int m = 1; m < 64; m <<= 1) acc[v] += __shfl_xor(acc[v], m, 64);
  }
  if ((t & 63) == 0) {
#pragma unroll
    for (int v = 0; v < 32; ++v) sw[(t >> 6) * 32 + v] = acc[v];
  }
  __syncthreads();
  if (t < 32)
    ctx[(((size_t)(b * 8 + h)) * 32 + kk) * 32 + t] =
        sw[t] + sw[32 + t] + sw[64 + t] + sw[96 + t];
}

// ------- m2_build: M2T[b][e][h*32+kk] = sum_v ctx[b][h][kk][v] * w_rep[h*32+v][e] -------
__global__ __launch_bounds__(256) void m2_build(
    const float* __restrict__ ctx, const u16* __restrict__ w_rept,
    u16* __restrict__ m2t) {
  const int b = blockIdx.x >> 4, ec = blockIdx.x & 15;
  const int t = threadIdx.x;
  const int e = ec * 32 + (t >> 3), h = t & 7;
  __shared__ float cl[8192];
#pragma unroll
  for (int i = 0; i < 8; ++i)
    *(float4*)(cl + t * 32 + i * 4) = *(const float4*)(ctx + b * 8192 + t * 32 + i * 4);
  __syncthreads();
  float wf[32];
  {
    u16 wv[32];
#pragma unroll
    for (int i = 0; i < 4; ++i)
      *(uint4*)(wv + i * 8) = *(const uint4*)(w_rept + (size_t)e * 256 + h * 32 + i * 8);
#pragma unroll
    for (int v = 0; v < 32; ++v) wf[v] = bf2f(wv[v]);
  }
  u16 outv[32];
#pragma unroll
  for (int kk = 0; kk < 32; ++kk) {
    float acc = 0.f;
    const float* cp = cl + h * 1024 + kk * 32;
#pragma unroll
    for (int v = 0; v < 32; ++v) acc += cp[v] * wf[v];
    outv[kk] = f2bf(acc);
  }
  u16* dst = m2t + ((size_t)(b * 512 + e)) * 256 + h * 32;
#pragma unroll
  for (int i = 0; i < 4; ++i) *(uint4*)(dst + i * 8) = *(uint4*)(outv + i * 8);
}

// ------- l3: rep = LN(rep_b); tx = concat(x1e,x2)+rep; txln = LN(tx) -------
__global__ __launch_bounds__(256) void l3_reptx(
    const u16* __restrict__ rep_b, const u16* __restrict__ x1e,
    const float* __restrict__ x2,
    const float* __restrict__ g_an, const float* __restrict__ be_an,
    const float* __restrict__ g_n2, const float* __restrict__ be_n2,
    u16* __restrict__ tx, u16* __restrict__ txln) {
  const int row = blockIdx.x, t = threadIdx.x;
  __shared__ float ws[8];
  float a0 = bf2f(rep_b[(size_t)row * DD2 + t]);
  float a1 = bf2f(rep_b[(size_t)row * DD2 + 256 + t]);
  float s = a0 + a1, q = a0 * a0 + a1 * a1;
#pragma unroll
  for (int m = 1; m < 64; m <<= 1) {
    s += __shfl_xor(s, m, 64);
    q += __shfl_xor(q, m, 64);
  }
  if ((t & 63) == 0) { ws[t >> 6] = s; ws[4 + (t >> 6)] = q; }
  __syncthreads();
  s = ws[0] + ws[1] + ws[2] + ws[3];
  q = ws[4] + ws[5] + ws[6] + ws[7];
  float mean = s * (1.0f / DD2);
  float var = q * (1.0f / DD2) - mean * mean;
  float iv = rsqrtf(var + 1e-5f);
  float r0 = (a0 - mean) * iv * g_an[t] + be_an[t];
  float r1 = (a1 - mean) * iv * g_an[256 + t] + be_an[256 + t];
  float t0 = bf2f(x1e[(size_t)row * DD + t]) + r0;
  float t1 = x2[(size_t)row * DD + t] + r1;
  tx[(size_t)row * DD2 + t] = f2bf(t0);
  tx[(size_t)row * DD2 + 256 + t] = f2bf(t1);
  __syncthreads();
  s = t0 + t1; q = t0 * t0 + t1 * t1;
#pragma unroll
  for (int m = 1; m < 64; m <<= 1) {
    s += __shfl_xor(s, m, 64);
    q += __shfl_xor(q, m, 64);
  }
  if ((t & 63) == 0) { ws[t >> 6] = s; ws[4 + (t >> 6)] = q; }
  __syncthreads();
  s = ws[0] + ws[1] + ws[2] + ws[3];
  q = ws[4] + ws[5] + ws[6] + ws[7];
  mean = s * (1.0f / DD2);
  var = q * (1.0f / DD2) - mean * mean;
  iv = rsqrtf(var + 1e-5f);
  txln[(size_t)row * DD2 + t] = f2bf((t0 - mean) * iv * g_n2[t] + be_n2[t]);
  txln[(size_t)row * DD2 + 256 + t] = f2bf((t1 - mean) * iv * g_n2[256 + t] + be_n2[256 + t]);
}

// ------- c8a_col: z-column dw-conv3d + skip + LN + GELU, PACKED fp16 math -------
// 1024 blocks x 512 threads, 2 channels/thread packed in _Float16x2.
// Conv taps are v_pk_fma_f16 (2 FMAs/inst, no unpack) -> ~3-4x fewer VALU ops
// than the scalar-bf16 form that plateaued at 74us.
__global__ __launch_bounds__(512) void c8a_col(
    const u16* __restrict__ h, const unsigned* __restrict__ w_dwh,
    const float* __restrict__ b_dw, const float* __restrict__ g,
    const float* __restrict__ be, u16* __restrict__ ax) {
  const int bid = blockIdx.x;
  const int cidx = (bid & 7) * 128 + (bid >> 3);  // XCD-chunked, bijective
  const int b = cidx >> 8, y = (cidx >> 4) & 15, x = cidx & 15;
  const int t = threadIdx.x;           // channel pair
  const int c0 = t * 2;
  const int lane = t & 63, wave = t >> 6;  // 8 waves
  const size_t hb = (size_t)b * NN * CC2;

  __shared__ float2 red[16][8];
  __shared__ float2 stats[16];

  int coln[9];
  float cmask[9];
#pragma unroll
  for (int dy = -1; dy <= 1; ++dy)
#pragma unroll
    for (int dx = -1; dx <= 1; ++dx) {
      int qq = (dy + 1) * 3 + (dx + 1);
      int yy = y + dy, xx = x + dx;
      bool ok = ((unsigned)yy < 16u) && ((unsigned)xx < 16u);
      coln[qq] = ((ok ? yy : y) << 4) | (ok ? xx : x);
      cmask[qq] = ok ? 1.f : 0.f;
    }

  // packed weights, pre-masked: wr[p][qq] = w_pair * mask
  h2 wr[3][9];
#pragma unroll
  for (int p = 0; p < 3; ++p)
#pragma unroll
    for (int qq = 0; qq < 9; ++qq) {
      union { unsigned u; h2 h; } w;
      w.u = w_dwh[(p * 9 + qq) * 512 + t];
      _Float16 m = (_Float16)cmask[qq];
      wr[p][qq] = w.h * (h2){m, m};
    }
  h2 bias2 = {(_Float16)b_dw[c0], (_Float16)b_dw[c0 + 1]};

  union { unsigned u; h2 h; } win[3][9];
#define LOADPLANE(ZL, SLOT)                                                   \
  do {                                                                        \
    if ((ZL) >= 0 && (ZL) < 16) {                                             \
      _Pragma("unroll") for (int qq = 0; qq < 9; ++qq) win[SLOT][qq].u =      \
          *(const unsigned*)(h + hb + (size_t)((((ZL) << 8) | coln[qq])) * CC2 + c0); \
    } else {                                                                  \
      _Pragma("unroll") for (int qq = 0; qq < 9; ++qq) win[SLOT][qq].u = 0u;  \
    }                                                                         \
  } while (0)

  LOADPLANE(-1, 0);
  LOADPLANE(0, 1);
  LOADPLANE(1, 2);

  unsigned vs[16];
#pragma unroll
  for (int z = 0; z < 16; ++z) {
    const int pm1 = z % 3, pz = (z + 1) % 3, pp1 = (z + 2) % 3;
    h2 acc = bias2;
#pragma unroll
    for (int qq = 0; qq < 9; ++qq) {
      acc = win[pm1][qq].h * wr[0][qq] + acc;   // v_pk_fma_f16
      acc = win[pz][qq].h * wr[1][qq] + acc;
      acc = win[pp1][qq].h * wr[2][qq] + acc;
    }
    acc = acc + win[pz][4].h;  // skip-add (center)
    LOADPLANE(z + 2, pm1);     // prefetch into dead slot
    union { h2 h; unsigned u; } pk; pk.h = acc;
    vs[z] = pk.u;
    float v0 = (float)acc[0], v1 = (float)acc[1];
    float s = v0 + v1, q2 = v0 * v0 + v1 * v1;
#pragma unroll
    for (int m = 1; m < 64; m <<= 1) {
      s += __shfl_xor(s, m, 64);
      q2 += __shfl_xor(q2, m, 64);
    }
    if (lane == 0) red[z][wave] = make_float2(s, q2);
  }
#undef LOADPLANE
  __syncthreads();

  // 8 waves: wave w reduces z=w and z=w+8
  for (int zz = wave; zz < 16; zz += 8) {
    float S = (lane < 8) ? red[zz][lane].x : 0.f;
    float Q = (lane < 8) ? red[zz][lane].y : 0.f;
#pragma unroll
    for (int m = 1; m < 8; m <<= 1) {
      S += __shfl_xor(S, m, 64);
      Q += __shfl_xor(Q, m, 64);
    }
    if (lane == 0) {
      float mean = S * (1.0f / CC2);
      float var = Q * (1.0f / CC2) - mean * mean;
      stats[zz] = make_float2(mean, rsqrtf(var + 1e-5f));
    }
  }
  __syncthreads();

  const float g0 = g[c0], g1 = g[c0 + 1], b0 = be[c0], b1 = be[c0 + 1];
#pragma unroll
  for (int z = 0; z < 16; ++z) {
    float2 st = stats[z];
    union { unsigned u; h2 h; } pv; pv.u = vs[z];
    float u0 = ((float)pv.h[0] - st.x) * st.y * g0 + b0;
    float u1 = ((float)pv.h[1] - st.x) * st.y * g1 + b1;
    float s0 = 1.5957691216f * (u0 + 0.044715f * u0 * u0 * u0);
    float s1 = 1.5957691216f * (u1 + 0.044715f * u1 * u1 * u1);
    float o0 = u0 / (1.0f + __expf(-s0));
    float o1 = u1 / (1.0f + __expf(-s1));
    unsigned pk = (unsigned)f2h(o0) | ((unsigned)f2h(o1) << 16);
    *(unsigned*)(ax + ((size_t)(b * NN + ((z << 8) | (y << 4) | x))) * CC2 + c0) = pk;
  }
}

extern "C" void kernel_launch(void* const* d_in, const int* in_sizes, int n_in,
                              void* d_out, int out_size, void* d_ws, size_t ws_size,
                              hipStream_t stream) {
  const float* x1    = (const float*)d_in[0];
  const float* x2    = (const float*)d_in[1];
  const float* w_x1  = (const float*)d_in[2];
  const float* b_x1  = (const float*)d_in[3];
  const float* g_n1  = (const float*)d_in[4];
  const float* be_n1 = (const float*)d_in[5];
  const float* w_rep = (const float*)d_in[6];
  const float* b_rep = (const float*)d_in[7];
  const float* g_an  = (const float*)d_in[8];
  const float* be_an = (const float*)d_in[9];
  const float* g_n2  = (const float*)d_in[10];
  const float* be_n2 = (const float*)d_in[11];
  const float* w_fc1 = (const float*)d_in[12];
  const float* b_fc1 = (const float*)d_in[13];
  const float* w_dw  = (const float*)d_in[14];
  const float* b_dw  = (const float*)d_in[15];
  const float* g_m1  = (const float*)d_in[16];
  const float* be_m1 = (const float*)d_in[17];
  const float* w_fc2 = (const float*)d_in[18];
  const float* b_fc2 = (const float*)d_in[19];
  const float* w_cat = (const float*)d_in[20];
  const float* b_cat = (const float*)d_in[21];
  const float* w_exp = (const float*)d_in[22];
  const float* g_up  = (const float*)d_in[23];
  const float* be_up = (const float*)d_in[24];

  char* ws = (char*)d_ws;
  float* out = (float*)d_out;

  u16*   qmat    = (u16*)(ws + 0);          // 8MB; then ybuf
  u16*   x1e_b   = (u16*)(ws + 8 * MB);     // bf16 x1e; then mx
  u16*   n1T     = (u16*)(ws + 24 * MB);
  u16*   n2T     = (u16*)(ws + 40 * MB);
  float* ctx     = (float*)(ws + 48 * MB);
  u16*   rep_b   = (u16*)(ws + 49 * MB);    // bf16 rep; then ax (fp16)
  u16*   tx      = (u16*)(ws + 81 * MB);
  u16*   txln    = (u16*)(ws + 97 * MB);
  u16*   hbuf    = (u16*)(ws + 113 * MB);   // fp16
  u16*   ax      = (u16*)(ws + 49 * MB);    // fp16
  u16*   mx      = (u16*)(ws + 8 * MB);
  u16*   ybuf    = (u16*)(ws + 0);
  u16*   w_x1t   = (u16*)(ws + 145 * MB);
  u16*   w_rept  = w_x1t + 256 * 256;
  u16*   w_fc1t  = w_rept + 512 * 256;
  u16*   w_fc2h  = w_fc1t + 1024 * 512;     // fp16 [512][1024]
  u16*   w_catt  = w_fc2h + 512 * 1024;     // [256][512]
  u16*   w_expt  = w_catt + 256 * 512;      // [1024][256]
  unsigned* w_dwh = (unsigned*)(ws + 149 * MB);  // [27][512] packed fp16
  u16*   m2t     = (u16*)(ws + 152 * MB);   // [4][512][256] bf16

  wprep_all<<<(1652224 + 255) / 256, 256, 0, stream>>>(
      w_x1, w_rep, w_fc1, w_fc2, w_cat, w_exp, w_dw,
      w_x1t, w_rept, w_fc1t, w_fc2h, w_catt, w_expt, w_dwh);

  gemm_mfma<256, 1, true><<<(ROWS / 128) * 2, 256, 0, stream>>>(
      (const u16*)x1, w_x1t, b_x1, nullptr, x1e_b, 2, nullptr, nullptr);
  ln256_both<<<2 * ROWS, 256, 0, stream>>>(x1e_b, x2, g_n1, be_n1, n1T, n2T, qmat);
  k34_ctx<<<BB * 256, 256, 0, stream>>>(n2T, n1T, ctx);
  m2_build<<<64, 256, 0, stream>>>(ctx, w_rept, m2t);
  gemm_mfma<256, 1, false, true><<<(ROWS / 128) * 4, 256, 0, stream>>>(
      qmat, m2t, b_rep, nullptr, rep_b, 4, nullptr, nullptr);
  l3_reptx<<<ROWS, 256, 0, stream>>>(rep_b, x1e_b, x2, g_an, be_an, g_n2, be_n2, tx, txln);
  // fc1 -> hbuf in fp16
  gemm_mfma<512, 4><<<(ROWS / 128) * 8, 256, 0, stream>>>(
      txln, w_fc1t, b_fc1, nullptr, hbuf, 8, nullptr, nullptr);
  c8a_col<<<1024, 512, 0, stream>>>(hbuf, w_dwh, b_dw, g_m1, be_m1, ax);
  // fc2: fp16 A/B mfma, bf16 residual tx, bf16 out mx
  gemm_mfma<1024, 2, false, false, true><<<(ROWS / 128) * 4, 256, 0, stream>>>(
      ax, w_fc2h, b_fc2, tx, mx, 4, nullptr, nullptr);
  gemm_mfma<512, 1><<<(ROWS / 128) * 2, 256, 0, stream>>>(
      mx, w_catt, b_cat, nullptr, ybuf, 2, nullptr, nullptr);
  gemm_mfma<256, 3><<<(ROWS / 128) * 8, 256, 0, stream>>>(
      ybuf, w_expt, nullptr, nullptr, out, 8, g_up, be_up);
}

// Round 14
// 271.488 us; speedup vs baseline: 1.2078x; 1.1077x over previous
//
#include <hip/hip_runtime.h>
#include <math.h>

using u16 = unsigned short;
typedef __bf16 bf16x8 __attribute__((ext_vector_type(8)));
typedef _Float16 h16x8 __attribute__((ext_vector_type(8)));
typedef _Float16 h2 __attribute__((ext_vector_type(2)));
typedef float f32x4 __attribute__((ext_vector_type(4)));

#define BB 4
#define NN 4096
#define DD 256
#define DD2 512
#define CC2 1024
static constexpr int ROWS = BB * NN;  // 16384
static constexpr size_t MB = 1024 * 1024;

__device__ __forceinline__ u16 f2bf(float f) {
  union { float f; unsigned u; } v; v.f = f;
  unsigned r = v.u + 0x7fffu + ((v.u >> 16) & 1u);
  return (u16)(r >> 16);
}
__device__ __forceinline__ float bf2f(u16 u) {
  union { unsigned u; float f; } v; v.u = ((unsigned)u) << 16;
  return v.f;
}
__device__ __forceinline__ u16 f2h(float f) {
  union { _Float16 h; u16 u; } v; v.h = (_Float16)f; return v.u;
}
__device__ __forceinline__ void gload16(const void* g, void* l) {
  __builtin_amdgcn_global_load_lds(
      (const __attribute__((address_space(1))) void*)g,
      (__attribute__((address_space(3))) void*)l, 16, 0, 0);
}

// ---------------- one-shot weight prep ----------------
__global__ __launch_bounds__(256) void wprep_all(
    const float* __restrict__ w_x1, const float* __restrict__ w_rep,
    const float* __restrict__ w_fc1, const float* __restrict__ w_fc2,
    const float* __restrict__ w_cat, const float* __restrict__ w_exp,
    const float* __restrict__ w_dw,
    u16* __restrict__ w_x1t, u16* __restrict__ w_rept,
    u16* __restrict__ w_fc1t, u16* __restrict__ w_fc2h,
    u16* __restrict__ w_catt, u16* __restrict__ w_expt,
    unsigned* __restrict__ w_dwh) {
  int i = blockIdx.x * 256 + threadIdx.x;
  if (i < 65536) { int n = i >> 8, k = i & 255; w_x1t[i] = f2bf(w_x1[k * 256 + n]); return; }
  i -= 65536;
  if (i < 131072) { int n = i >> 8, k = i & 255; w_rept[i] = f2bf(w_rep[k * 512 + n]); return; }
  i -= 131072;
  if (i < 524288) { int n = i >> 9, k = i & 511; w_fc1t[i] = f2bf(w_fc1[k * 1024 + n]); return; }
  i -= 524288;
  if (i < 524288) { int n = i >> 10, k = i & 1023; w_fc2h[i] = f2h(w_fc2[k * 512 + n]); return; }
  i -= 524288;
  if (i < 131072) { int n = i >> 9, k = i & 511; w_catt[i] = f2bf(w_cat[k * 256 + n]); return; }
  i -= 131072;
  if (i < 262144) { int n = i >> 8, k = i & 255; w_expt[i] = f2bf(w_exp[k * 1024 + n]); return; }
  i -= 262144;
  if (i < 13824) {
    int tap = i >> 9, cp = i & 511;
    unsigned lo = f2h(w_dw[(2 * cp) * 27 + tap]);
    unsigned hi = f2h(w_dw[(2 * cp + 1) * 27 + tap]);
    w_dwh[i] = lo | (hi << 16);
  }
}

// ---------------- generic 128x128-tile MFMA GEMM ----------------
// A [M][K], Bt [N][K], C row-major [M][Ncols]
// AF32: A fp32 converted in-register. PERB: Bt per-batch. F16: fp16 MFMA.
// EPI: 0 f32 | 1 bf16 | 2 bf16 + bf16-resid | 3 f32 + fused 128-col LN | 4 fp16
template <int K, int EPI, bool AF32 = false, bool PERB = false, bool F16 = false>
__global__ __launch_bounds__(256, 2) void gemm_mfma(
    const u16* __restrict__ A, const u16* __restrict__ Bt,
    const float* __restrict__ bias, const u16* __restrict__ resid,
    void* __restrict__ Cout, int nTilesN,
    const float* __restrict__ gup, const float* __restrict__ beup) {
  const int t = threadIdx.x;
  const int bid = blockIdx.x;
  const int m0 = (bid / nTilesN) * 128;
  const int n0 = (bid % nTilesN) * 128;
  const int Ncols = nTilesN * 128;
  if (PERB) Bt += (size_t)(m0 >> 12) * (size_t)Ncols * K;
  const int lane = t & 63, wid = t >> 6;
  const int wr = wid >> 1, wc = wid & 1;
  const int lrow = lane & 15, kgrp = lane >> 4;

  __shared__ u16 ldsA[2][128 * 32];
  __shared__ u16 ldsB[2][128 * 32];

  int srow[2], sslot[2];
#pragma unroll
  for (int c = 0; c < 2; ++c) {
    int idx = c * 256 + t;
    srow[c] = idx >> 2;
    sslot[c] = (idx & 3) ^ ((srow[c] >> 1) & 3);
  }

  int offA[4], offB[4];
#pragma unroll
  for (int m = 0; m < 4; ++m) {
    int r = wr * 64 + m * 16 + lrow;
    offA[m] = r * 32 + ((kgrp ^ ((r >> 1) & 3)) * 8);
  }
#pragma unroll
  for (int n = 0; n < 4; ++n) {
    int r = wc * 64 + n * 16 + lrow;
    offB[n] = r * 32 + ((kgrp ^ ((r >> 1) & 3)) * 8);
  }

  f32x4 acc[4][4];
#pragma unroll
  for (int m = 0; m < 4; ++m)
#pragma unroll
    for (int n = 0; n < 4; ++n) acc[m][n] = f32x4{0.f, 0.f, 0.f, 0.f};

  auto loadA32 = [&](int c, int kc) -> uint4 {
    const float* A32 = (const float*)A;
    const float* p = A32 + (size_t)(m0 + srow[c]) * K + kc + sslot[c] * 8;
    float4 f0 = *(const float4*)p;
    float4 f1 = *(const float4*)(p + 4);
    u16 o[8] = {f2bf(f0.x), f2bf(f0.y), f2bf(f0.z), f2bf(f0.w),
                f2bf(f1.x), f2bf(f1.y), f2bf(f1.z), f2bf(f1.w)};
    return *(uint4*)o;
  };
  auto stage_async = [&](int buf, int kc) {
#pragma unroll
    for (int c = 0; c < 2; ++c) {
      gload16(A + (size_t)(m0 + srow[c]) * K + kc + sslot[c] * 8,
              &ldsA[buf][(c * 256 + t) * 8]);
      gload16(Bt + (size_t)(n0 + srow[c]) * K + kc + sslot[c] * 8,
              &ldsB[buf][(c * 256 + t) * 8]);
    }
  };

  uint4 ra[2], rb[2];
  if constexpr (AF32) {
#pragma unroll
    for (int c = 0; c < 2; ++c) {
      ra[c] = loadA32(c, 0);
      rb[c] = *(const uint4*)(Bt + (size_t)(n0 + srow[c]) * K + sslot[c] * 8);
    }
#pragma unroll
    for (int c = 0; c < 2; ++c) {
      int idx = c * 256 + t;
      *(uint4*)&ldsA[0][idx * 8] = ra[c];
      *(uint4*)&ldsB[0][idx * 8] = rb[c];
    }
  } else {
    stage_async(0, 0);
  }
  __syncthreads();

  const int nt = K / 32;
  for (int tt = 0; tt < nt; ++tt) {
    const int cur = tt & 1;
    if (tt + 1 < nt) {
      const int kc = (tt + 1) * 32;
      if constexpr (AF32) {
#pragma unroll
        for (int c = 0; c < 2; ++c) {
          ra[c] = loadA32(c, kc);
          rb[c] = *(const uint4*)(Bt + (size_t)(n0 + srow[c]) * K + kc + sslot[c] * 8);
        }
      } else {
        stage_async(cur ^ 1, kc);
      }
    }
    if constexpr (F16) {
      h16x8 af[4], bf[4];
#pragma unroll
      for (int m = 0; m < 4; ++m) af[m] = *(const h16x8*)&ldsA[cur][offA[m]];
#pragma unroll
      for (int n = 0; n < 4; ++n) bf[n] = *(const h16x8*)&ldsB[cur][offB[n]];
#pragma unroll
      for (int m = 0; m < 4; ++m)
#pragma unroll
        for (int n = 0; n < 4; ++n)
          acc[m][n] = __builtin_amdgcn_mfma_f32_16x16x32_f16(af[m], bf[n], acc[m][n], 0, 0, 0);
    } else {
      bf16x8 af[4], bf[4];
#pragma unroll
      for (int m = 0; m < 4; ++m) af[m] = *(const bf16x8*)&ldsA[cur][offA[m]];
#pragma unroll
      for (int n = 0; n < 4; ++n) bf[n] = *(const bf16x8*)&ldsB[cur][offB[n]];
#pragma unroll
      for (int m = 0; m < 4; ++m)
#pragma unroll
        for (int n = 0; n < 4; ++n)
          acc[m][n] = __builtin_amdgcn_mfma_f32_16x16x32_bf16(af[m], bf[n], acc[m][n], 0, 0, 0);
    }
    if (AF32 && tt + 1 < nt) {
#pragma unroll
      for (int c = 0; c < 2; ++c) {
        int idx = c * 256 + t;
        *(uint4*)&ldsA[cur ^ 1][idx * 8] = ra[c];
        *(uint4*)&ldsB[cur ^ 1][idx * 8] = rb[c];
      }
    }
    __syncthreads();
  }

  if (EPI == 3) {
    __shared__ float lnS[2][128], lnQ[2][128];
    float s_[4][4], q_[4][4];
#pragma unroll
    for (int m = 0; m < 4; ++m)
#pragma unroll
      for (int j = 0; j < 4; ++j) {
        float s = 0.f, q = 0.f;
#pragma unroll
        for (int n = 0; n < 4; ++n) {
          float v = acc[m][n][j];
          s += v; q += v * v;
        }
        s_[m][j] = s; q_[m][j] = q;
      }
#pragma unroll
    for (int msk = 1; msk < 16; msk <<= 1) {
#pragma unroll
      for (int m = 0; m < 4; ++m)
#pragma unroll
        for (int j = 0; j < 4; ++j) {
          s_[m][j] += __shfl_xor(s_[m][j], msk, 64);
          q_[m][j] += __shfl_xor(q_[m][j], msk, 64);
        }
    }
    if (lrow == 0) {
#pragma unroll
      for (int m = 0; m < 4; ++m)
#pragma unroll
        for (int j = 0; j < 4; ++j) {
          int r = wr * 64 + m * 16 + kgrp * 4 + j;
          lnS[wc][r] = s_[m][j];
          lnQ[wc][r] = q_[m][j];
        }
    }
    __syncthreads();
#pragma unroll
    for (int m = 0; m < 4; ++m) {
      const int rb0 = wr * 64 + m * 16 + kgrp * 4;
#pragma unroll
      for (int j = 0; j < 4; ++j) {
        const int r = rb0 + j;
        float S = lnS[0][r] + lnS[1][r];
        float Q = lnQ[0][r] + lnQ[1][r];
        float mean = S * (1.0f / 128.0f);
        float var = Q * (1.0f / 128.0f) - mean * mean;
        float iv = rsqrtf(var + 1e-5f);
#pragma unroll
        for (int n = 0; n < 4; ++n) {
          int lc = wc * 64 + n * 16 + lrow;
          ((float*)Cout)[(size_t)(m0 + r) * Ncols + n0 + lc] =
              (acc[m][n][j] - mean) * iv * gup[lc] + beup[lc];
        }
      }
    }
    return;
  }

  float bcol[4];
#pragma unroll
  for (int n = 0; n < 4; ++n) {
    int col = n0 + wc * 64 + n * 16 + (lane & 15);
    bcol[n] = bias ? bias[col] : 0.f;
  }
#pragma unroll
  for (int m = 0; m < 4; ++m) {
    const int r0 = m0 + wr * 64 + m * 16 + kgrp * 4;
#pragma unroll
    for (int n = 0; n < 4; ++n) {
      const int col = n0 + wc * 64 + n * 16 + (lane & 15);
#pragma unroll
      for (int j = 0; j < 4; ++j) {
        float v = acc[m][n][j] + bcol[n];
        size_t idx = (size_t)(r0 + j) * Ncols + col;
        if (EPI == 0) {
          ((float*)Cout)[idx] = v;
        } else if (EPI == 1) {
          ((u16*)Cout)[idx] = f2bf(v);
        } else if (EPI == 4) {
          ((u16*)Cout)[idx] = f2h(v);
        } else {
          v += bf2f(resid[idx]);
          ((u16*)Cout)[idx] = f2bf(v);
        }
      }
    }
  }
}

// ------- ln_tr: tiled LN with COALESCED transposed output -------
// blocks [0,512): x1e-stream -> n1T.  [512,1024): x2-stream -> n2T + x2b(raw) + qmat.
// One wave per row (lane = 4 channels, wave-local reduce); LDS tile [32][264];
// transposed store as uint4 (batch-LOCAL token index: n = row & 4095).
__global__ __launch_bounds__(256) void ln_tr(
    const u16* __restrict__ x1e_b, const float* __restrict__ x2,
    const float* __restrict__ g, const float* __restrict__ be,
    u16* __restrict__ n1T, u16* __restrict__ n2T,
    u16* __restrict__ x2b, u16* __restrict__ qmat) {
  int bid = blockIdx.x;
  const bool first = bid < 512;
  if (!first) bid -= 512;
  const int r0 = bid * 32;
  const int b = r0 >> 12;
  const int nloc = r0 & (NN - 1);  // batch-local token base (BUGFIX r12)
  const int t = threadIdx.x;
  const int lane = t & 63, wave = t >> 6;
  const int d0 = lane * 4;
  __shared__ u16 tile[32][264];

  float gv[4], bv[4];
#pragma unroll
  for (int j = 0; j < 4; ++j) { gv[j] = g[d0 + j]; bv[j] = be[d0 + j]; }

#pragma unroll
  for (int it = 0; it < 8; ++it) {
    const int row = r0 + it * 4 + wave;
    float v[4];
    if (first) {
      uint2 u = *(const uint2*)(x1e_b + (size_t)row * DD + d0);
      v[0] = bf2f((u16)(u.x & 0xffff)); v[1] = bf2f((u16)(u.x >> 16));
      v[2] = bf2f((u16)(u.y & 0xffff)); v[3] = bf2f((u16)(u.y >> 16));
    } else {
      float4 f = *(const float4*)(x2 + (size_t)row * DD + d0);
      v[0] = f.x; v[1] = f.y; v[2] = f.z; v[3] = f.w;
      u16 raw[4] = {f2bf(f.x), f2bf(f.y), f2bf(f.z), f2bf(f.w)};
      *(uint2*)(x2b + (size_t)row * DD + d0) = *(uint2*)raw;  // raw x2 for residual
    }
    float s = v[0] + v[1] + v[2] + v[3];
    float q = v[0] * v[0] + v[1] * v[1] + v[2] * v[2] + v[3] * v[3];
#pragma unroll
    for (int m = 1; m < 64; m <<= 1) {
      s += __shfl_xor(s, m, 64);
      q += __shfl_xor(q, m, 64);
    }
    float mean = s * (1.0f / DD);
    float var = q * (1.0f / DD) - mean * mean;
    float iv = rsqrtf(var + 1e-5f);
    const int rit = it * 4 + wave;
    u16 o[4];
#pragma unroll
    for (int j = 0; j < 4; ++j) o[j] = f2bf((v[j] - mean) * iv * gv[j] + bv[j]);
    *(uint2*)&tile[rit][d0] = *(uint2*)o;
    if (!first) {
      // per-head (32-ch = 8-lane group) softmax -> qmat
      float lb[4] = {bf2f(o[0]), bf2f(o[1]), bf2f(o[2]), bf2f(o[3])};
      float hm = fmaxf(fmaxf(lb[0], lb[1]), fmaxf(lb[2], lb[3]));
#pragma unroll
      for (int m = 1; m < 8; m <<= 1) hm = fmaxf(hm, __shfl_xor(hm, m, 64));
      float he[4], hs = 0.f;
#pragma unroll
      for (int j = 0; j < 4; ++j) { he[j] = __expf(lb[j] - hm); hs += he[j]; }
#pragma unroll
      for (int m = 1; m < 8; m <<= 1) hs += __shfl_xor(hs, m, 64);
      float inv = 1.0f / hs;
      u16 qo[4];
#pragma unroll
      for (int j = 0; j < 4; ++j) qo[j] = f2bf(he[j] * inv);
      *(uint2*)(qmat + (size_t)row * DD + d0) = *(uint2*)qo;
    }
  }
  __syncthreads();

  u16* dstT = first ? n1T : n2T;
#pragma unroll
  for (int i = 0; i < 4; ++i) {
    int chunk = i * 256 + t;
    int d = chunk >> 2, nc = chunk & 3;
    u16 vals[8];
#pragma unroll
    for (int k = 0; k < 8; ++k) vals[k] = tile[nc * 8 + k][d];
    *(uint4*)(dstT + ((size_t)(b * 256 + d)) * 4096 + nloc + nc * 8) = *(uint4*)vals;
  }
}

// ------- k34: fused column-softmax stats + ctx -------
__global__ __launch_bounds__(256) void k34_ctx(
    const u16* __restrict__ n2T, const u16* __restrict__ n1T,
    float* __restrict__ ctx) {
  const int bid = blockIdx.x;
  const int bx = (bid & 7) * 128 + (bid >> 3);
  const int b = bx >> 8, d = bx & 255;
  const int h = d >> 5, kk = d & 31;
  const int t = threadIdx.x;
  __shared__ u16 prow[4096];
  __shared__ float xred[8];
  __shared__ float sw[128];
  const u16* src = n2T + (size_t)bx * 4096;
  ((uint4*)prow)[t] = ((const uint4*)src)[t];
  ((uint4*)prow)[256 + t] = ((const uint4*)src)[256 + t];
  __syncthreads();
  float mx = -1e30f;
#pragma unroll
  for (int i = 0; i < 16; ++i) mx = fmaxf(mx, bf2f(prow[i * 256 + t]));
#pragma unroll
  for (int m = 1; m < 64; m <<= 1) mx = fmaxf(mx, __shfl_xor(mx, m, 64));
  if ((t & 63) == 0) xred[t >> 6] = mx;
  __syncthreads();
  mx = fmaxf(fmaxf(xred[0], xred[1]), fmaxf(xred[2], xred[3]));
  float sme = 0.f;
#pragma unroll
  for (int i = 0; i < 16; ++i) sme += __expf(bf2f(prow[i * 256 + t]) - mx);
#pragma unroll
  for (int m = 1; m < 64; m <<= 1) sme += __shfl_xor(sme, m, 64);
  if ((t & 63) == 0) xred[4 + (t >> 6)] = sme;
  __syncthreads();
  const float inv = 1.0f / (xred[4] + xred[5] + xred[6] + xred[7]);

  float acc[32];
#pragma unroll
  for (int v = 0; v < 32; ++v) acc[v] = 0.f;
  const u16* vbase = n1T + ((size_t)(b * 256 + h * 32)) * 4096;
  for (int i = 0; i < 16; ++i) {
    const int n = i * 256 + t;
    const float p = __expf(bf2f(prow[n]) - mx) * inv;
#pragma unroll
    for (int v = 0; v < 32; ++v)
      acc[v] += p * bf2f(vbase[(size_t)v * 4096 + n]);
  }
#pragma unroll
  for (int v = 0; v < 32; ++v) {
#pragma unroll
    for (int m = 1; m < 64; m <<= 1) acc[v] += __shfl_xor(acc[v], m, 64);
  }
  if ((t & 63) == 0) {
#pragma unroll
    for (int v = 0; v < 32; ++v) sw[(t >> 6) * 32 + v] = acc[v];
  }
  __syncthreads();
  if (t < 32)
    ctx[(((size_t)(b * 8 + h)) * 32 + kk) * 32 + t] =
        sw[t] + sw[32 + t] + sw[64 + t] + sw[96 + t];
}

// ------- m2_build -------
__global__ __launch_bounds__(256) void m2_build(
    const float* __restrict__ ctx, const u16* __restrict__ w_rept,
    u16* __restrict__ m2t) {
  const int b = blockIdx.x >> 4, ec = blockIdx.x & 15;
  const int t = threadIdx.x;
  const int e = ec * 32 + (t >> 3), h = t & 7;
  __shared__ float cl[8192];
#pragma unroll
  for (int i = 0; i < 8; ++i)
    *(float4*)(cl + t * 32 + i * 4) = *(const float4*)(ctx + b * 8192 + t * 32 + i * 4);
  __syncthreads();
  float wf[32];
  {
    u16 wv[32];
#pragma unroll
    for (int i = 0; i < 4; ++i)
      *(uint4*)(wv + i * 8) = *(const uint4*)(w_rept + (size_t)e * 256 + h * 32 + i * 8);
#pragma unroll
    for (int v = 0; v < 32; ++v) wf[v] = bf2f(wv[v]);
  }
  u16 outv[32];
#pragma unroll
  for (int kk = 0; kk < 32; ++kk) {
    float acc = 0.f;
    const float* cp = cl + h * 1024 + kk * 32;
#pragma unroll
    for (int v = 0; v < 32; ++v) acc += cp[v] * wf[v];
    outv[kk] = f2bf(acc);
  }
  u16* dst = m2t + ((size_t)(b * 512 + e)) * 256 + h * 32;
#pragma unroll
  for (int i = 0; i < 4; ++i) *(uint4*)(dst + i * 8) = *(uint4*)(outv + i * 8);
}

// ------- l3: rep = LN(rep_b); tx = concat(x1e,x2b)+rep; txln = LN(tx) (all bf16) -------
__global__ __launch_bounds__(256) void l3_reptx(
    const u16* __restrict__ rep_b, const u16* __restrict__ x1e,
    const u16* __restrict__ x2b,
    const float* __restrict__ g_an, const float* __restrict__ be_an,
    const float* __restrict__ g_n2, const float* __restrict__ be_n2,
    u16* __restrict__ tx, u16* __restrict__ txln) {
  const int row = blockIdx.x, t = threadIdx.x;
  __shared__ float ws[8];
  float a0 = bf2f(rep_b[(size_t)row * DD2 + t]);
  float a1 = bf2f(rep_b[(size_t)row * DD2 + 256 + t]);
  float s = a0 + a1, q = a0 * a0 + a1 * a1;
#pragma unroll
  for (int m = 1; m < 64; m <<= 1) {
    s += __shfl_xor(s, m, 64);
    q += __shfl_xor(q, m, 64);
  }
  if ((t & 63) == 0) { ws[t >> 6] = s; ws[4 + (t >> 6)] = q; }
  __syncthreads();
  s = ws[0] + ws[1] + ws[2] + ws[3];
  q = ws[4] + ws[5] + ws[6] + ws[7];
  float mean = s * (1.0f / DD2);
  float var = q * (1.0f / DD2) - mean * mean;
  float iv = rsqrtf(var + 1e-5f);
  float r0 = (a0 - mean) * iv * g_an[t] + be_an[t];
  float r1 = (a1 - mean) * iv * g_an[256 + t] + be_an[256 + t];
  float t0 = bf2f(x1e[(size_t)row * DD + t]) + r0;
  float t1 = bf2f(x2b[(size_t)row * DD + t]) + r1;
  tx[(size_t)row * DD2 + t] = f2bf(t0);
  tx[(size_t)row * DD2 + 256 + t] = f2bf(t1);
  __syncthreads();
  s = t0 + t1; q = t0 * t0 + t1 * t1;
#pragma unroll
  for (int m = 1; m < 64; m <<= 1) {
    s += __shfl_xor(s, m, 64);
    q += __shfl_xor(q, m, 64);
  }
  if ((t & 63) == 0) { ws[t >> 6] = s; ws[4 + (t >> 6)] = q; }
  __syncthreads();
  s = ws[0] + ws[1] + ws[2] + ws[3];
  q = ws[4] + ws[5] + ws[6] + ws[7];
  mean = s * (1.0f / DD2);
  var = q * (1.0f / DD2) - mean * mean;
  iv = rsqrtf(var + 1e-5f);
  txln[(size_t)row * DD2 + t] = f2bf((t0 - mean) * iv * g_n2[t] + be_n2[t]);
  txln[(size_t)row * DD2 + 256 + t] = f2bf((t1 - mean) * iv * g_n2[256 + t] + be_n2[256 + t]);
}

// ------- c8a_col: packed-fp16 dw-conv3d + skip + LN + GELU -------
__global__ __launch_bounds__(512) void c8a_col(
    const u16* __restrict__ h, const unsigned* __restrict__ w_dwh,
    const float* __restrict__ b_dw, const float* __restrict__ g,
    const float* __restrict__ be, u16* __restrict__ ax) {
  const int bid = blockIdx.x;
  const int cidx = (bid & 7) * 128 + (bid >> 3);
  const int b = cidx >> 8, y = (cidx >> 4) & 15, x = cidx & 15;
  const int t = threadIdx.x;
  const int c0 = t * 2;
  const int lane = t & 63, wave = t >> 6;
  const size_t hb = (size_t)b * NN * CC2;

  __shared__ float2 red[16][8];
  __shared__ float2 stats[16];

  int coln[9];
  float cmask[9];
#pragma unroll
  for (int dy = -1; dy <= 1; ++dy)
#pragma unroll
    for (int dx = -1; dx <= 1; ++dx) {
      int qq = (dy + 1) * 3 + (dx + 1);
      int yy = y + dy, xx = x + dx;
      bool ok = ((unsigned)yy < 16u) && ((unsigned)xx < 16u);
      coln[qq] = ((ok ? yy : y) << 4) | (ok ? xx : x);
      cmask[qq] = ok ? 1.f : 0.f;
    }

  h2 wr[3][9];
#pragma unroll
  for (int p = 0; p < 3; ++p)
#pragma unroll
    for (int qq = 0; qq < 9; ++qq) {
      union { unsigned u; h2 h; } w;
      w.u = w_dwh[(p * 9 + qq) * 512 + t];
      _Float16 m = (_Float16)cmask[qq];
      wr[p][qq] = w.h * (h2){m, m};
    }
  h2 bias2 = {(_Float16)b_dw[c0], (_Float16)b_dw[c0 + 1]};

  union { unsigned u; h2 h; } win[3][9];
#define LOADPLANE(ZL, SLOT)                                                   \
  do {                                                                        \
    if ((ZL) >= 0 && (ZL) < 16) {                                             \
      _Pragma("unroll") for (int qq = 0; qq < 9; ++qq) win[SLOT][qq].u =      \
          *(const unsigned*)(h + hb + (size_t)((((ZL) << 8) | coln[qq])) * CC2 + c0); \
    } else {                                                                  \
      _Pragma("unroll") for (int qq = 0; qq < 9; ++qq) win[SLOT][qq].u = 0u;  \
    }                                                                         \
  } while (0)

  LOADPLANE(-1, 0);
  LOADPLANE(0, 1);
  LOADPLANE(1, 2);

  unsigned vs[16];
#pragma unroll
  for (int z = 0; z < 16; ++z) {
    const int pm1 = z % 3, pz = (z + 1) % 3, pp1 = (z + 2) % 3;
    h2 acc = bias2;
#pragma unroll
    for (int qq = 0; qq < 9; ++qq) {
      acc = win[pm1][qq].h * wr[0][qq] + acc;
      acc = win[pz][qq].h * wr[1][qq] + acc;
      acc = win[pp1][qq].h * wr[2][qq] + acc;
    }
    acc = acc + win[pz][4].h;
    LOADPLANE(z + 2, pm1);
    union { h2 h; unsigned u; } pk; pk.h = acc;
    vs[z] = pk.u;
    float v0 = (float)acc[0], v1 = (float)acc[1];
    float s = v0 + v1, q2 = v0 * v0 + v1 * v1;
#pragma unroll
    for (int m = 1; m < 64; m <<= 1) {
      s += __shfl_xor(s, m, 64);
      q2 += __shfl_xor(q2, m, 64);
    }
    if (lane == 0) red[z][wave] = make_float2(s, q2);
  }
#undef LOADPLANE
  __syncthreads();

  for (int zz = wave; zz < 16; zz += 8) {
    float S = (lane < 8) ? red[zz][lane].x : 0.f;
    float Q = (lane < 8) ? red[zz][lane].y : 0.f;
#pragma unroll
    for (int m = 1; m < 8; m <<= 1) {
      S += __shfl_xor(S, m, 64);
      Q += __shfl_xor(Q, m, 64);
    }
    if (lane == 0) {
      float mean = S * (1.0f / CC2);
      float var = Q * (1.0f / CC2) - mean * mean;
      stats[zz] = make_float2(mean, rsqrtf(var + 1e-5f));
    }
  }
  __syncthreads();

  const float g0 = g[c0], g1 = g[c0 + 1], b0 = be[c0], b1 = be[c0 + 1];
#pragma unroll
  for (int z = 0; z < 16; ++z) {
    float2 st = stats[z];
    union { unsigned u; h2 h; } pv; pv.u = vs[z];
    float u0 = ((float)pv.h[0] - st.x) * st.y * g0 + b0;
    float u1 = ((float)pv.h[1] - st.x) * st.y * g1 + b1;
    float s0 = 1.5957691216f * (u0 + 0.044715f * u0 * u0 * u0);
    float s1 = 1.5957691216f * (u1 + 0.044715f * u1 * u1 * u1);
    float o0 = u0 / (1.0f + __expf(-s0));
    float o1 = u1 / (1.0f + __expf(-s1));
    unsigned pk = (unsigned)f2h(o0) | ((unsigned)f2h(o1) << 16);
    *(unsigned*)(ax + ((size_t)(b * NN + ((z << 8) | (y << 4) | x))) * CC2 + c0) = pk;
  }
}

extern "C" void kernel_launch(void* const* d_in, const int* in_sizes, int n_in,
                              void* d_out, int out_size, void* d_ws, size_t ws_size,
                              hipStream_t stream) {
  const float* x1    = (const float*)d_in[0];
  const float* x2    = (const float*)d_in[1];
  const float* w_x1  = (const float*)d_in[2];
  const float* b_x1  = (const float*)d_in[3];
  const float* g_n1  = (const float*)d_in[4];
  const float* be_n1 = (const float*)d_in[5];
  const float* w_rep = (const float*)d_in[6];
  const float* b_rep = (const float*)d_in[7];
  const float* g_an  = (const float*)d_in[8];
  const float* be_an = (const float*)d_in[9];
  const float* g_n2  = (const float*)d_in[10];
  const float* be_n2 = (const float*)d_in[11];
  const float* w_fc1 = (const float*)d_in[12];
  const float* b_fc1 = (const float*)d_in[13];
  const float* w_dw  = (const float*)d_in[14];
  const float* b_dw  = (const float*)d_in[15];
  const float* g_m1  = (const float*)d_in[16];
  const float* be_m1 = (const float*)d_in[17];
  const float* w_fc2 = (const float*)d_in[18];
  const float* b_fc2 = (const float*)d_in[19];
  const float* w_cat = (const float*)d_in[20];
  const float* b_cat = (const float*)d_in[21];
  const float* w_exp = (const float*)d_in[22];
  const float* g_up  = (const float*)d_in[23];
  const float* be_up = (const float*)d_in[24];

  char* ws = (char*)d_ws;
  float* out = (float*)d_out;

  u16*   qmat    = (u16*)(ws + 0);
  u16*   x1e_b   = (u16*)(ws + 8 * MB);
  u16*   n1T     = (u16*)(ws + 24 * MB);
  u16*   x2bb    = (u16*)(ws + 32 * MB);
  u16*   n2T     = (u16*)(ws + 40 * MB);
  float* ctx     = (float*)(ws + 48 * MB);
  u16*   rep_b   = (u16*)(ws + 49 * MB);
  u16*   tx      = (u16*)(ws + 81 * MB);
  u16*   txln    = (u16*)(ws + 97 * MB);
  u16*   hbuf    = (u16*)(ws + 113 * MB);
  u16*   ax      = (u16*)(ws + 49 * MB);
  u16*   mx      = (u16*)(ws + 8 * MB);
  u16*   ybuf    = (u16*)(ws + 0);
  u16*   w_x1t   = (u16*)(ws + 145 * MB);
  u16*   w_rept  = w_x1t + 256 * 256;
  u16*   w_fc1t  = w_rept + 512 * 256;
  u16*   w_fc2h  = w_fc1t + 1024 * 512;
  u16*   w_catt  = w_fc2h + 512 * 1024;
  u16*   w_expt  = w_catt + 256 * 512;
  unsigned* w_dwh = (unsigned*)(ws + 149 * MB);
  u16*   m2t     = (u16*)(ws + 152 * MB);

  wprep_all<<<(1652224 + 255) / 256, 256, 0, stream>>>(
      w_x1, w_rep, w_fc1, w_fc2, w_cat, w_exp, w_dw,
      w_x1t, w_rept, w_fc1t, w_fc2h, w_catt, w_expt, w_dwh);

  gemm_mfma<256, 1, true><<<(ROWS / 128) * 2, 256, 0, stream>>>(
      (const u16*)x1, w_x1t, b_x1, nullptr, x1e_b, 2, nullptr, nullptr);
  ln_tr<<<1024, 256, 0, stream>>>(x1e_b, x2, g_n1, be_n1, n1T, n2T, x2bb, qmat);
  k34_ctx<<<BB * 256, 256, 0, stream>>>(n2T, n1T, ctx);
  m2_build<<<64, 256, 0, stream>>>(ctx, w_rept, m2t);
  gemm_mfma<256, 1, false, true><<<(ROWS / 128) * 4, 256, 0, stream>>>(
      qmat, m2t, b_rep, nullptr, rep_b, 4, nullptr, nullptr);
  l3_reptx<<<ROWS, 256, 0, stream>>>(rep_b, x1e_b, x2bb, g_an, be_an,
                                     g_n2, be_n2, tx, txln);
  gemm_mfma<512, 4><<<(ROWS / 128) * 8, 256, 0, stream>>>(
      txln, w_fc1t, b_fc1, nullptr, hbuf, 8, nullptr, nullptr);
  c8a_col<<<1024, 512, 0, stream>>>(hbuf, w_dwh, b_dw, g_m1, be_m1, ax);
  gemm_mfma<1024, 2, false, false, true><<<(ROWS / 128) * 4, 256, 0, stream>>>(
      ax, w_fc2h, b_fc2, tx, mx, 4, nullptr, nullptr);
  gemm_mfma<512, 1><<<(ROWS / 128) * 2, 256, 0, stream>>>(
      mx, w_catt, b_cat, nullptr, ybuf, 2, nullptr, nullptr);
  gemm_mfma<256, 3><<<(ROWS / 128) * 8, 256, 0, stream>>>(
      ybuf, w_expt, nullptr, nullptr, out, 8, g_up, be_up);
}